// Round 6
// baseline (263.097 us; speedup 1.0000x reference)
//
#include <hip/hip_runtime.h>

// ParticleKernel: B=4, N=2048, D=512, P=16, K=4
// k0_all: fused preprocess (charge->bf16, Wc->bf16, pos hi/lo splits + |p|^2)
// K1 : projm_t[c][b*N+j] = bf16( mass * charge @ Wc^T )   — dbuf, 1 barrier/iter, 3 blk/CU
// K2 : field[b*N+i][c] = bf16( sum_j exp2(s2*dist2)*projm_t[c][j] ); dist2 via MFMA Gram hi/lo.
//      j-tile 32, triple-buffered Bs + dbuf Wl, ONE barrier/iter (staging issued a full
//      iteration before its drain). XCD-aware block mapping keeps projm slice L2-resident.
// K3 : out = field @ Wcb^T (fp32 into d_out) — dbuf, 1 barrier/iter
// K4 : LayerNorm in place.

typedef __bf16 bf16x8 __attribute__((ext_vector_type(8)));
typedef float f32x4 __attribute__((ext_vector_type(4)));

__device__ __forceinline__ unsigned short f2bf(float f) {
    unsigned u = __float_as_uint(f);
    unsigned r = (u + 0x7fffu + ((u >> 16) & 1u)) >> 16;
    return (unsigned short)r;
}
__device__ __forceinline__ float bf2f(unsigned short h) {
    return __uint_as_float(((unsigned)h) << 16);
}
__device__ __forceinline__ void g2l16(const unsigned short* g, unsigned short* l) {
    __builtin_amdgcn_global_load_lds(
        (const __attribute__((address_space(1))) unsigned int*)g,
        (__attribute__((address_space(3))) unsigned int*)l, 16, 0, 0);
}

// ---------------- k0_all: fused preprocess ----------------
// blocks [0,4096): charge cvt; [4096,5120): Wc cvt; [5120,5152): pos preprocess
__global__ __launch_bounds__(256) void k0_all(const float* __restrict__ charge,
                                              const float* __restrict__ Wc,
                                              const float* __restrict__ pos,
                                              unsigned short* __restrict__ ch16,
                                              unsigned short* __restrict__ wc16,
                                              unsigned short* __restrict__ posA,
                                              unsigned short* __restrict__ posB1,
                                              unsigned short* __restrict__ posB2,
                                              float* __restrict__ rsq)
{
    const int bx = blockIdx.x, tid = threadIdx.x;
    if (bx < 5120) {
        const float* src = (bx < 4096) ? charge : Wc;
        unsigned short* dst = (bx < 4096) ? ch16 : wc16;
        size_t i = (size_t)(bx < 4096 ? bx : bx - 4096) * 256 + tid;
        float4 v = reinterpret_cast<const float4*>(src)[i];
        unsigned short o[4] = {f2bf(v.x), f2bf(v.y), f2bf(v.z), f2bf(v.w)};
        reinterpret_cast<uint2*>(dst)[i] = *reinterpret_cast<uint2*>(&o[0]);
        return;
    }
    const int row = (bx - 5120) * 256 + tid;  // 0..8191
    const float* src = &pos[(size_t)row * 16];
    float p[16];
#pragma unroll
    for (int cc = 0; cc < 4; cc++) {
        float4 v = *reinterpret_cast<const float4*>(&src[cc * 4]);
        p[cc * 4 + 0] = v.x; p[cc * 4 + 1] = v.y; p[cc * 4 + 2] = v.z; p[cc * 4 + 3] = v.w;
    }
    float r = 0.f;
    unsigned short h[16], lo[16], z[8] = {0, 0, 0, 0, 0, 0, 0, 0};
#pragma unroll
    for (int d = 0; d < 16; d++) {
        r = __builtin_fmaf(p[d], p[d], r);
        h[d] = f2bf(p[d]);
        lo[d] = f2bf(p[d] - bf2f(h[d]));
    }
    rsq[row] = r;
    size_t o = (size_t)row * 32;
    *reinterpret_cast<int4*>(&posA[o + 0])   = *reinterpret_cast<int4*>(&h[0]);
    *reinterpret_cast<int4*>(&posA[o + 8])   = *reinterpret_cast<int4*>(&h[8]);
    *reinterpret_cast<int4*>(&posA[o + 16])  = *reinterpret_cast<int4*>(&lo[0]);
    *reinterpret_cast<int4*>(&posA[o + 24])  = *reinterpret_cast<int4*>(&lo[8]);
    *reinterpret_cast<int4*>(&posB1[o + 0])  = *reinterpret_cast<int4*>(&h[0]);
    *reinterpret_cast<int4*>(&posB1[o + 8])  = *reinterpret_cast<int4*>(&h[8]);
    *reinterpret_cast<int4*>(&posB1[o + 16]) = *reinterpret_cast<int4*>(&h[0]);
    *reinterpret_cast<int4*>(&posB1[o + 24]) = *reinterpret_cast<int4*>(&h[8]);
    *reinterpret_cast<int4*>(&posB2[o + 0])  = *reinterpret_cast<int4*>(&lo[0]);
    *reinterpret_cast<int4*>(&posB2[o + 8])  = *reinterpret_cast<int4*>(&lo[8]);
    *reinterpret_cast<int4*>(&posB2[o + 16]) = *reinterpret_cast<int4*>(&z[0]);
    *reinterpret_cast<int4*>(&posB2[o + 24]) = *reinterpret_cast<int4*>(&z[0]);
}

// ---------------- K0c: bulk fp32 -> bf16 convert (Wcb, after K2) ----------------
__global__ __launch_bounds__(256) void k0_cvt(const float* __restrict__ src,
                                              unsigned short* __restrict__ dst)
{
    size_t i = (size_t)blockIdx.x * 256 + threadIdx.x;
    float4 v = reinterpret_cast<const float4*>(src)[i];
    unsigned short o[4] = {f2bf(v.x), f2bf(v.y), f2bf(v.z), f2bf(v.w)};
    reinterpret_cast<uint2*>(dst)[i] = *reinterpret_cast<uint2*>(&o[0]);
}

// ---------------- K1: projection GEMM, dbuf single-barrier ----------------
// C[m=c][n=b*N+j] = sum_k Wc16[m][k]*ch16[n][k];  M=2048, N=8192, K=512
__global__ __launch_bounds__(256, 3) void k1_proj(const unsigned short* __restrict__ wc16,
                                                  const unsigned short* __restrict__ ch16,
                                                  const float* __restrict__ mass,
                                                  unsigned short* __restrict__ projm_t)
{
    __shared__ alignas(16) unsigned short As[2][128 * 32];  // 16 KB
    __shared__ alignas(16) unsigned short Bs[2][128 * 32];  // 16 KB
    const int tid = threadIdx.x, lane = tid & 63, wid = tid >> 6;
    const int q = lane >> 4, l15 = lane & 15;
    const int sw = (l15 >> 2) & 3;
    const int m0 = blockIdx.y * 128, n0 = blockIdx.x * 128;
    const int wm = (wid & 1) * 64, wn = (wid >> 1) * 64;

    f32x4 acc[4][4];
#pragma unroll
    for (int i = 0; i < 4; i++)
#pragma unroll
        for (int j = 0; j < 4; j++) acc[i][j] = (f32x4){0.f, 0.f, 0.f, 0.f};

    // chunk decode for staging (512 chunks A + 512 B per k-step)
    const int w = tid & 255;  // reused below with q4
    (void)w;

    // prologue: stage k0=0 into buf 0
#pragma unroll
    for (int q4 = 0; q4 < 4; q4++) {
        int chunk = q4 * 256 + tid;
        int ww = chunk & 511, row = ww >> 2;
        int gc4 = (ww & 3) ^ ((ww >> 4) & 3);
        if (chunk < 512)
            g2l16(&wc16[(size_t)(m0 + row) * 512 + gc4 * 8], &As[0][ww * 8]);
        else
            g2l16(&ch16[(size_t)(n0 + row) * 512 + gc4 * 8], &Bs[0][ww * 8]);
    }
    __syncthreads();

    for (int n = 0; n < 16; n++) {
        const int p = n & 1;
        const int k1 = (n + 1) * 32;
        if (k1 < 512) {
#pragma unroll
            for (int q4 = 0; q4 < 4; q4++) {
                int chunk = q4 * 256 + tid;
                int ww = chunk & 511, row = ww >> 2;
                int gc4 = (ww & 3) ^ ((ww >> 4) & 3);
                if (chunk < 512)
                    g2l16(&wc16[(size_t)(m0 + row) * 512 + k1 + gc4 * 8], &As[p ^ 1][ww * 8]);
                else
                    g2l16(&ch16[(size_t)(n0 + row) * 512 + k1 + gc4 * 8], &Bs[p ^ 1][ww * 8]);
            }
        }
        bf16x8 af[4], bfr[4];
#pragma unroll
        for (int it = 0; it < 4; it++)
            af[it] = *reinterpret_cast<const bf16x8*>(&As[p][(wm + it * 16 + l15) * 32 + (q ^ sw) * 8]);
#pragma unroll
        for (int ct = 0; ct < 4; ct++)
            bfr[ct] = *reinterpret_cast<const bf16x8*>(&Bs[p][(wn + ct * 16 + l15) * 32 + (q ^ sw) * 8]);
#pragma unroll
        for (int it = 0; it < 4; it++)
#pragma unroll
            for (int ct = 0; ct < 4; ct++)
                acc[it][ct] = __builtin_amdgcn_mfma_f32_16x16x32_bf16(af[it], bfr[ct], acc[it][ct], 0, 0, 0);
        __syncthreads();
    }
#pragma unroll
    for (int ct = 0; ct < 4; ct++) {
        int nn = n0 + wn + ct * 16 + l15;
        float mf = mass[nn];
#pragma unroll
        for (int it = 0; it < 4; it++) {
            int mrow = m0 + wm + it * 16 + q * 4;
#pragma unroll
            for (int r = 0; r < 4; r++)
                projm_t[(size_t)(mrow + r) * 8192 + nn] = f2bf(acc[it][ct][r] * mf);
        }
    }
}

// ---------------- K2: fused Gram + exp + field GEMM, 128i x 256c, 1 barrier/iter ----------------
__global__ __launch_bounds__(256, 2) void k2_field(const unsigned short* __restrict__ posA,
                                                   const unsigned short* __restrict__ posB1,
                                                   const unsigned short* __restrict__ posB2,
                                                   const float* __restrict__ rsq,
                                                   const float* __restrict__ logbw,
                                                   const unsigned short* __restrict__ projm_t,
                                                   unsigned short* __restrict__ field)
{
    __shared__ alignas(16) unsigned short Bs[3][256 * 32];  // 48 KB, triple-buffered
    __shared__ alignas(16) unsigned short Wl[2][128 * 40];  // 20 KB, double-buffered

    const int tid = threadIdx.x, lane = tid & 63, wid = tid >> 6;
    const int q = lane >> 4, l15 = lane & 15;
    const int sw = (l15 >> 2) & 3;
    // XCD-aware decode (round-robin workgroup->XCD by linear id; perf heuristic only)
    const int L = blockIdx.x;
    const int xcd = L & 7, idx = L >> 3;
    const int i_t = idx & 15, cb = xcd * 4 + (idx >> 4);
    const int c0 = (cb & 7) * 256, b = cb >> 3;
    const int i0 = i_t * 128;
    const int kb = c0 >> 9;
    const float bw = __expf(logbw[kb]);
    const float s2 = -1.4426950408889634f / (2.0f * bw + 1e-8f);  // w = exp2(dist2*s2)
    const float c2 = -2.0f * s2;
    const int bN = b * 2048;

    // loop-invariant Gram A-frags + ri*s2 (wave wid owns Wl rows [wid*32, wid*32+32))
    bf16x8 afG[2];
    float riS2[2][4];
#pragma unroll
    for (int t = 0; t < 2; t++) {
        afG[t] = *reinterpret_cast<const bf16x8*>(
            &posA[(size_t)(bN + i0 + wid * 32 + t * 16 + l15) * 32 + q * 8]);
#pragma unroll
        for (int r = 0; r < 4; r++)
            riS2[t][r] = rsq[bN + i0 + wid * 32 + t * 16 + q * 4 + r] * s2;
    }

    const int wo_i = (wid >> 1) * 64, wo_c = (wid & 1) * 128;
    const size_t gbase = (size_t)c0 * 8192 + bN;

    f32x4 acc[4][8];
#pragma unroll
    for (int i = 0; i < 4; i++)
#pragma unroll
        for (int j = 0; j < 8; j++) acc[i][j] = (f32x4){0.f, 0.f, 0.f, 0.f};

    // prologue: stage j0=0 into Bs[0] (no barrier needed; first body barrier drains it)
#pragma unroll
    for (int q4 = 0; q4 < 4; q4++) {
        int chunk = q4 * 256 + tid;
        int row = chunk >> 2, gc4 = (chunk & 3) ^ ((chunk >> 4) & 3);
        g2l16(&projm_t[gbase + (size_t)row * 8192 + gc4 * 8], &Bs[0][chunk * 8]);
    }

    int bs_r = 0;  // read buffer for this iter; staging targets (bs_r+1)%3
    for (int n = 0; n < 64; n++) {
        const int j0 = n * 32;
        const int p = n & 1;
        // ---- gram global loads first (in-order VMEM: gram waits only on these) ----
        bf16x8 gb1[2], gb2[2];
        float rj2[2];
#pragma unroll
        for (int jt2 = 0; jt2 < 2; jt2++) {
            int j = bN + j0 + jt2 * 16 + l15;
            gb1[jt2] = *reinterpret_cast<const bf16x8*>(&posB1[(size_t)j * 32 + q * 8]);
            gb2[jt2] = *reinterpret_cast<const bf16x8*>(&posB2[(size_t)j * 32 + q * 8]);
            rj2[jt2] = rsq[j] * s2;
        }
        // ---- issue staging for j0+32 into Bs[(bs_r+1)%3] (drains at THIS iter's barrier) ----
        if (j0 + 32 < 2048) {
            const int bs_w = bs_r + 1 == 3 ? 0 : bs_r + 1;
            const size_t gb = gbase + j0 + 32;
#pragma unroll
            for (int q4 = 0; q4 < 4; q4++) {
                int chunk = q4 * 256 + tid;
                int row = chunk >> 2, gc4 = (chunk & 3) ^ ((chunk >> 4) & 3);
                g2l16(&projm_t[gb + (size_t)row * 8192 + gc4 * 8], &Bs[bs_w][chunk * 8]);
            }
        }
        // ---- gram MFMA + exp (covers the staging in flight) ----
#pragma unroll
        for (int jt2 = 0; jt2 < 2; jt2++) {
#pragma unroll
            for (int t = 0; t < 2; t++) {
                f32x4 g = (f32x4){0.f, 0.f, 0.f, 0.f};
                g = __builtin_amdgcn_mfma_f32_16x16x32_bf16(afG[t], gb2[jt2], g, 0, 0, 0);
                g = __builtin_amdgcn_mfma_f32_16x16x32_bf16(afG[t], gb1[jt2], g, 0, 0, 0);
#pragma unroll
                for (int r = 0; r < 4; r++) {
                    float x = __builtin_fmaf(g[r], c2, riS2[t][r] + rj2[jt2]);
                    Wl[p][(wid * 32 + t * 16 + q * 4 + r) * 40 + jt2 * 16 + l15] =
                        f2bf(__builtin_amdgcn_exp2f(x));
                }
            }
        }
        __syncthreads();  // single barrier: Wl[p] visible, Bs[bs_r] (staged last iter) drained
        // ---- field MFMA from Bs[bs_r] + Wl[p] ----
        bf16x8 af[4], bfr[8];
#pragma unroll
        for (int it = 0; it < 4; it++)
            af[it] = *reinterpret_cast<const bf16x8*>(&Wl[p][(wo_i + it * 16 + l15) * 40 + q * 8]);
#pragma unroll
        for (int ct = 0; ct < 8; ct++)
            bfr[ct] = *reinterpret_cast<const bf16x8*>(&Bs[bs_r][(wo_c + ct * 16 + l15) * 32 + (q ^ sw) * 8]);
#pragma unroll
        for (int it = 0; it < 4; it++)
#pragma unroll
            for (int ct = 0; ct < 8; ct++)
                acc[it][ct] = __builtin_amdgcn_mfma_f32_16x16x32_bf16(af[it], bfr[ct], acc[it][ct], 0, 0, 0);
        bs_r = bs_r + 1 == 3 ? 0 : bs_r + 1;
    }
#pragma unroll
    for (int it = 0; it < 4; it++) {
#pragma unroll
        for (int ct = 0; ct < 8; ct++) {
            int gi = bN + i0 + wo_i + it * 16 + q * 4;
            int gc = c0 + wo_c + ct * 16 + l15;
#pragma unroll
            for (int r = 0; r < 4; r++)
                field[(size_t)(gi + r) * 2048 + gc] = f2bf(acc[it][ct][r]);
        }
    }
}

// ---------------- K3: combine GEMM, 64m x 128n, dbuf single-barrier ----------------
// C[m=b*N+i][n=dout] = sum_c field[m][c]*wcb16[n][c]; M=8192, N=512, K=2048
__global__ __launch_bounds__(256, 3) void k3_combine(const unsigned short* __restrict__ field,
                                                     const unsigned short* __restrict__ wcb16,
                                                     float* __restrict__ out)
{
    __shared__ alignas(16) unsigned short As[2][64 * 32];   // 8 KB
    __shared__ alignas(16) unsigned short Bs[2][128 * 32];  // 16 KB
    const int tid = threadIdx.x, lane = tid & 63, wid = tid >> 6;
    const int q = lane >> 4, l15 = lane & 15;
    const int sw = (l15 >> 2) & 3;
    const int m0 = blockIdx.y * 64, n0 = blockIdx.x * 128;
    const int wn = wid * 32;

    f32x4 acc[4][2];
#pragma unroll
    for (int i = 0; i < 4; i++)
#pragma unroll
        for (int j = 0; j < 2; j++) acc[i][j] = (f32x4){0.f, 0.f, 0.f, 0.f};

    // prologue: stage k0=0 into buf 0
#pragma unroll
    for (int q3 = 0; q3 < 3; q3++) {
        int chunk = q3 * 256 + tid;
        if (chunk < 256) {
            int row = chunk >> 2, gc4 = (chunk & 3) ^ ((chunk >> 4) & 3);
            g2l16(&field[(size_t)(m0 + row) * 2048 + gc4 * 8], &As[0][chunk * 8]);
        } else {
            int ww = chunk - 256, row = ww >> 2, gc4 = (ww & 3) ^ ((ww >> 4) & 3);
            g2l16(&wcb16[(size_t)(n0 + row) * 2048 + gc4 * 8], &Bs[0][ww * 8]);
        }
    }
    __syncthreads();

    for (int n = 0; n < 64; n++) {
        const int p = n & 1;
        const int k1 = (n + 1) * 32;
        if (k1 < 2048) {
#pragma unroll
            for (int q3 = 0; q3 < 3; q3++) {
                int chunk = q3 * 256 + tid;
                if (chunk < 256) {
                    int row = chunk >> 2, gc4 = (chunk & 3) ^ ((chunk >> 4) & 3);
                    g2l16(&field[(size_t)(m0 + row) * 2048 + k1 + gc4 * 8], &As[p ^ 1][chunk * 8]);
                } else {
                    int ww = chunk - 256, row = ww >> 2, gc4 = (ww & 3) ^ ((ww >> 4) & 3);
                    g2l16(&wcb16[(size_t)(n0 + row) * 2048 + k1 + gc4 * 8], &Bs[p ^ 1][ww * 8]);
                }
            }
        }
        bf16x8 af[4], bfr[2];
#pragma unroll
        for (int it = 0; it < 4; it++)
            af[it] = *reinterpret_cast<const bf16x8*>(&As[p][(it * 16 + l15) * 32 + (q ^ sw) * 8]);
#pragma unroll
        for (int ct = 0; ct < 2; ct++)
            bfr[ct] = *reinterpret_cast<const bf16x8*>(&Bs[p][(wn + ct * 16 + l15) * 32 + (q ^ sw) * 8]);
#pragma unroll
        for (int it = 0; it < 4; it++)
#pragma unroll
            for (int ct = 0; ct < 2; ct++)
                acc[it][ct] = __builtin_amdgcn_mfma_f32_16x16x32_bf16(af[it], bfr[ct], acc[it][ct], 0, 0, 0);
        __syncthreads();
    }
#pragma unroll
    for (int it = 0; it < 4; it++) {
#pragma unroll
        for (int ct = 0; ct < 2; ct++) {
            int m = m0 + it * 16 + q * 4;
            int nn = n0 + wn + ct * 16 + l15;
#pragma unroll
            for (int r = 0; r < 4; r++)
                out[(size_t)(m + r) * 512 + nn] = acc[it][ct][r];
        }
    }
}

// ---------------- K4: LayerNorm in place ----------------
__global__ __launch_bounds__(256) void k4_ln(float* __restrict__ out,
                                             const float* __restrict__ gamma,
                                             const float* __restrict__ beta)
{
    __shared__ float red[8];
    const int row = blockIdx.x, tid = threadIdx.x;
    float2 x = *reinterpret_cast<const float2*>(&out[(size_t)row * 512 + tid * 2]);
    float s = x.x + x.y;
    float ss = x.x * x.x + x.y * x.y;
#pragma unroll
    for (int off = 32; off > 0; off >>= 1) {
        s += __shfl_down(s, off);
        ss += __shfl_down(ss, off);
    }
    int wid = tid >> 6;
    if ((tid & 63) == 0) { red[wid * 2] = s; red[wid * 2 + 1] = ss; }
    __syncthreads();
    s = red[0] + red[2] + red[4] + red[6];
    ss = red[1] + red[3] + red[5] + red[7];
    float mean = s * (1.f / 512.f);
    float var = ss * (1.f / 512.f) - mean * mean;
    float inv = rsqrtf(var + 1e-5f);
    float g0 = gamma[tid * 2], g1 = gamma[tid * 2 + 1];
    float b0 = beta[tid * 2], b1 = beta[tid * 2 + 1];
    float2 o;
    o.x = (x.x - mean) * inv * g0 + b0;
    o.y = (x.y - mean) * inv * g1 + b1;
    *reinterpret_cast<float2*>(&out[(size_t)row * 512 + tid * 2]) = o;
}

extern "C" void kernel_launch(void* const* d_in, const int* in_sizes, int n_in,
                              void* d_out, int out_size, void* d_ws, size_t ws_size,
                              hipStream_t stream)
{
    const float* charge   = (const float*)d_in[0];
    const float* position = (const float*)d_in[1];
    const float* mass     = (const float*)d_in[2];
    const float* logbw    = (const float*)d_in[3];
    const float* Wc       = (const float*)d_in[4];
    const float* Wcb      = (const float*)d_in[5];
    const float* gamma    = (const float*)d_in[6];
    const float* beta     = (const float*)d_in[7];

    // ws layout: [0,32MB) projm_t (later aliased by wcb16) | [32,64MB) field (earlier aliased by ch16+wc16)
    unsigned short* projm_t = (unsigned short*)d_ws;
    unsigned short* field   = projm_t + (size_t)2048 * 8192;
    unsigned short* wcb16   = projm_t;                         // written after K2 (projm_t dead)
    unsigned short* ch16    = field;                           // dead before K2 writes field
    unsigned short* wc16    = field + (size_t)8192 * 512;
    // d_out as scratch for pos-derived arrays (dead before K3 writes out)
    unsigned short* posA  = (unsigned short*)d_out;            // 8192*32
    unsigned short* posB1 = posA + (size_t)8192 * 32;
    unsigned short* posB2 = posB1 + (size_t)8192 * 32;
    float* rsq = (float*)(posB2 + (size_t)8192 * 32);          // 8192 floats
    float* out = (float*)d_out;

    k0_all<<<5152, 256, 0, stream>>>(charge, Wc, position, ch16, wc16, posA, posB1, posB2, rsq);
    k1_proj<<<dim3(64, 16), 256, 0, stream>>>(wc16, ch16, mass, projm_t);
    k2_field<<<512, 256, 0, stream>>>(posA, posB1, posB2, rsq, logbw, projm_t, field);
    k0_cvt<<<1024, 256, 0, stream>>>(Wcb, wcb16);              // 512*2048
    k3_combine<<<dim3(4, 128), 256, 0, stream>>>(field, wcb16, out);
    k4_ln<<<8192, 256, 0, stream>>>(out, gamma, beta);
}